// Round 7
// baseline (1565.193 us; speedup 1.0000x reference)
//
#include <hip/hip_runtime.h>

#define T_STEPS 512
#define HID     64
#define NB      16    // batch cols per chain (MFMA N)
#define CH      8     // steps per xg burst chunk

typedef __attribute__((ext_vector_type(8))) short bf16x8;   // 8 bf16 = 4 VGPR
typedef __attribute__((ext_vector_type(8))) short short8v;  // 16B
typedef __attribute__((ext_vector_type(4))) float f32x4;

#define MFMA __builtin_amdgcn_mfma_f32_16x16x32_bf16

__device__ __forceinline__ unsigned short f2bf(float f) {   // RNE f32->bf16
    unsigned u = __float_as_uint(f);
    return (unsigned short)((u + 0x7fffu + ((u >> 16) & 1u)) >> 16);
}
__device__ __forceinline__ float bf2f(unsigned short h) {
    return __uint_as_float(((unsigned)h) << 16);
}
__device__ __forceinline__ float fast_tanh(float x) {
    return 1.0f - 2.0f * __builtin_amdgcn_rcpf(1.0f + __expf(2.0f * x));
}

// 32 blocks (one per 16-batch chain) x 1024 threads (16 waves).
// Wave w owns gate-tile m=w: gate rows [16w,16w+16) = gate gt=w>>2 (i,f,g,o),
// units [16*(w&3), +16). Frag roles (verified round 6): A row=l&15,
// A/B k=(l>>4)*8+j, C/D col=l&15, row=4*(l>>4)+r.
// Weights exact as bf16 hi+lo pairs; activations single bf16 (2-term MFMA).
// Per step: 4 h-MFMA + act -> acts LDS -> bar -> c/h update (thread tau owns
// (unit=tau>>4, col=tau&15)) -> Hs bf16 (parity dbuf) -> bar.
// xg (x-part) MFMA'd per CH-chunk into register C-frags, X frags read
// straight from global (L1-served redundancy), no LDS staging.
template<int LAYER>
__global__ __launch_bounds__(1024)
void lstm_big(const float* __restrict__ xin,          // L0: [B,T,32] fp32
              const unsigned short* __restrict__ hin, // L1: [32][T][16][64] bf16
              const float* __restrict__ W_ih,         // [256,K_IN]
              const float* __restrict__ W_hh,         // [256,64]
              const float* __restrict__ b_ih,
              const float* __restrict__ b_hh,
              unsigned short* __restrict__ hws,       // L0 out (= L1 hin)
              const float* __restrict__ W_fc,
              const float* __restrict__ b_fc,
              float* __restrict__ fcout)
{
    constexpr int K_IN = (LAYER == 0) ? 32 : 64;
    constexpr int KS_X = K_IN / 32;

    __shared__ unsigned short Hs[2][NB][72];     // h state, bf16, parity dbuf
    __shared__ float acts[4][HID][17];           // gate acts exchange
    __shared__ unsigned short hch[CH][NB][72];   // L0: h chunk staging
    __shared__ float red[16][17];                // L1: FC reduce

    const int tid = threadIdx.x;
    const int w   = tid >> 6;        // wave 0..15
    const int l   = tid & 63;
    const int col = l & 15;          // batch col (A-row & C-col share l&15)
    const int g4  = l >> 4;
    const int cc  = blockIdx.x;
    const int b0  = cc * NB;
    const int gt  = w >> 2;          // this wave's gate
    const int ug  = w & 3;           // this wave's unit-group
    const int cu  = tid >> 4;        // c/h phase: unit 0..63
    const int cl  = tid & 15;        // c/h phase: col

    // Branchless act per wave (uniform): sigmoid / tanh
    const float sA = (gt == 2) ? 2.0f : -1.0f;
    const float sB = (gt == 2) ? 1.0f : 0.0f;
    const float sC = (gt == 2) ? -2.0f : 1.0f;

    // ---- Weights: exact bf16 hi+lo A-fragments ----
    const int arow = 16 * w + col;
    bf16x8 whhH[2], whhL[2];
    #pragma unroll
    for (int ks = 0; ks < 2; ++ks) {
        const float* p = W_hh + (size_t)arow * HID + ks * 32 + 8 * g4;
        #pragma unroll
        for (int j = 0; j < 8; ++j) {
            float v = p[j];
            unsigned short h = f2bf(v);
            whhH[ks][j] = (short)h;
            whhL[ks][j] = (short)f2bf(v - bf2f(h));
        }
    }
    bf16x8 wihH[KS_X], wihL[KS_X];
    #pragma unroll
    for (int ks = 0; ks < KS_X; ++ks) {
        const float* p = W_ih + (size_t)arow * K_IN + ks * 32 + 8 * g4;
        #pragma unroll
        for (int j = 0; j < 8; ++j) {
            float v = p[j];
            unsigned short h = f2bf(v);
            wihH[ks][j] = (short)h;
            wihL[ks][j] = (short)f2bf(v - bf2f(h));
        }
    }
    f32x4 bias4;
    {
        const int br = 16 * w + 4 * g4;
        float4 bi = *(const float4*)(b_ih + br);
        float4 bh = *(const float4*)(b_hh + br);
        bias4 = (f32x4){bi.x + bh.x, bi.y + bh.y, bi.z + bh.z, bi.w + bh.w};
    }

    // ---- init state ----
    Hs[0][tid >> 6][tid & 63] = 0;      // covers [16][64]; pads never read
    float cstate = 0.0f;
    const float wfc = (LAYER == 1) ? W_fc[cu] : 0.0f;
    float part = 0.0f;
    __syncthreads();

    for (int c0 = 0; c0 < T_STEPS; c0 += CH) {
        // ---- burst: xg C-frags for CH steps (registers only) ----
        f32x4 xga[CH];
        #pragma unroll
        for (int tt = 0; tt < CH; ++tt) {
            f32x4 a = bias4;
            if (LAYER == 0) {
                const float* xp = xin + ((size_t)(b0 + col) * T_STEPS + (c0 + tt)) * 32 + 8 * g4;
                float4 v0 = *(const float4*)xp;
                float4 v1 = *(const float4*)(xp + 4);
                bf16x8 xb;
                xb[0] = (short)f2bf(v0.x); xb[1] = (short)f2bf(v0.y);
                xb[2] = (short)f2bf(v0.z); xb[3] = (short)f2bf(v0.w);
                xb[4] = (short)f2bf(v1.x); xb[5] = (short)f2bf(v1.y);
                xb[6] = (short)f2bf(v1.z); xb[7] = (short)f2bf(v1.w);
                a = MFMA(wihH[0], xb, a, 0, 0, 0);
                a = MFMA(wihL[0], xb, a, 0, 0, 0);
            } else {
                #pragma unroll
                for (int ks = 0; ks < 2; ++ks) {
                    bf16x8 xb = *(const bf16x8*)(hin +
                        (((size_t)cc * T_STEPS + (c0 + tt)) * NB + col) * HID + ks * 32 + 8 * g4);
                    a = MFMA(wihH[ks], xb, a, 0, 0, 0);
                    a = MFMA(wihL[ks], xb, a, 0, 0, 0);
                }
            }
            xga[tt] = a;
        }

        // ---- serial steps ----
        #pragma unroll
        for (int tt = 0; tt < CH; ++tt) {
            const int t = c0 + tt;
            const int p = t & 1;

            // phase 1: h-MFMA + activation (this wave's tile)
            f32x4 a = xga[tt];
            #pragma unroll
            for (int ks = 0; ks < 2; ++ks) {
                bf16x8 hb = *(const bf16x8*)&Hs[p][col][ks * 32 + 8 * g4];
                a = MFMA(whhH[ks], hb, a, 0, 0, 0);
                a = MFMA(whhL[ks], hb, a, 0, 0, 0);
            }
            #pragma unroll
            for (int r = 0; r < 4; ++r) {
                float av = sB + sC * __builtin_amdgcn_rcpf(1.0f + __expf(sA * a[r]));
                acts[gt][16 * ug + 4 * g4 + r][col] = av;
            }
            __syncthreads();   // acts visible

            // phase 2: c/h for (cu, cl) — thread-local state
            float i_ = acts[0][cu][cl];
            float f_ = acts[1][cu][cl];
            float g_ = acts[2][cu][cl];
            float o_ = acts[3][cu][cl];
            cstate = fmaf(f_, cstate, i_ * g_);
            float h = o_ * fast_tanh(cstate);
            unsigned short hb16 = f2bf(h);
            Hs[p ^ 1][cl][cu] = hb16;
            if (LAYER == 0) hch[tt][cl][cu] = hb16;
            if (LAYER == 1 && t == T_STEPS - 1) part = h * wfc;
            __syncthreads();   // h(t) visible; guards acts WAR
        }

        // ---- L0: coalesced flush of hch -> hws (reads precede next bar1) ----
        if (LAYER == 0) {
            const int ft = tid >> 7;          // 0..7
            const int fc = (tid >> 3) & 15;   // col
            const int u0 = (tid & 7) * 8;
            short8v v = *(const short8v*)&hch[ft][fc][u0];
            *(short8v*)&hws[(((size_t)cc * T_STEPS + c0 + ft) * NB + fc) * HID + u0] = v;
        }
    }

    if (LAYER == 1) {
        // FC: sum over units. Wave w holds units {4w..4w+3} per col in lanes.
        part += __shfl_xor(part, 16);
        part += __shfl_xor(part, 32);
        if (l < 16) red[w][l] = part;
        __syncthreads();
        if (tid < 16) {
            float s = b_fc[0];
            #pragma unroll
            for (int ww = 0; ww < 16; ++ww) s += red[ww][tid];
            fcout[b0 + tid] = s;
        }
    }
}

extern "C" void kernel_launch(void* const* d_in, const int* in_sizes, int n_in,
                              void* d_out, int out_size, void* d_ws, size_t ws_size,
                              hipStream_t stream) {
    const float* x     = (const float*)d_in[0];
    const float* W_ih0 = (const float*)d_in[1];
    const float* W_hh0 = (const float*)d_in[2];
    const float* b_ih0 = (const float*)d_in[3];
    const float* b_hh0 = (const float*)d_in[4];
    const float* W_ih1 = (const float*)d_in[5];
    const float* W_hh1 = (const float*)d_in[6];
    const float* b_ih1 = (const float*)d_in[7];
    const float* b_hh1 = (const float*)d_in[8];
    const float* W_fc  = (const float*)d_in[9];
    const float* b_fc  = (const float*)d_in[10];

    float* out = (float*)d_out;
    unsigned short* h1 = (unsigned short*)d_ws;  // [32][512][16][64] bf16 = 32 MB

    lstm_big<0><<<32, 1024, 0, stream>>>(x, nullptr, W_ih0, W_hh0, b_ih0, b_hh0,
                                         h1, nullptr, nullptr, nullptr);
    lstm_big<1><<<32, 1024, 0, stream>>>(nullptr, h1, W_ih1, W_hh1, b_ih1, b_hh1,
                                         nullptr, W_fc, b_fc, out);
}